// Round 7
// baseline (358.750 us; speedup 1.0000x reference)
//
#include <hip/hip_runtime.h>

typedef __bf16 bf16;
typedef __bf16 bf16x2 __attribute__((ext_vector_type(2)));
typedef __bf16 bf16x8 __attribute__((ext_vector_type(8)));
typedef float f32x4 __attribute__((ext_vector_type(4)));

#define S_LEN 4096
#define DMODEL 512
#define NHEAD 8
#define DHEAD 64
#define BATCH 2
#define M_ROWS (BATCH * S_LEN)   // 8192
#define K_DIM 512
#define QKV_LD 1536

// ---------------------------------------------------------------------------
// Dtype detection (R3-verified): flag = 1 if bf16 inputs, 0 if f32.
// ---------------------------------------------------------------------------
__global__ void detect_dtype(const unsigned int* __restrict__ x,
                             int* __restrict__ flag) {
  const int lane = threadIdx.x;  // 64 lanes
  int cnt = 0;
#pragma unroll
  for (int i = 0; i < 16; ++i) {
    const unsigned int w = x[lane * 16 + i];
    const unsigned int e = (w >> 7) & 0xFFu;
    cnt += (e >= 100u && e <= 140u) ? 1 : 0;
  }
#pragma unroll
  for (int off = 1; off < 64; off <<= 1) cnt += __shfl_xor(cnt, off);
  if (lane == 0) *flag = (cnt >= 700) ? 1 : 0;
}

__device__ __forceinline__ bf16x8 ld8(const void* p, size_t e, bool asF32) {
  if (asF32) {
    const float* q = (const float*)p + e;
    const float4 a = *(const float4*)q;
    const float4 b = *(const float4*)(q + 4);
    bf16x8 r;
    r[0] = (bf16)a.x; r[1] = (bf16)a.y; r[2] = (bf16)a.z; r[3] = (bf16)a.w;
    r[4] = (bf16)b.x; r[5] = (bf16)b.y; r[6] = (bf16)b.z; r[7] = (bf16)b.w;
    return r;
  }
  return *(const bf16x8*)((const bf16*)p + e);
}

__device__ __forceinline__ float ld1(const void* p, size_t e, bool asF32) {
  return asF32 ? ((const float*)p)[e] : (float)((const bf16*)p)[e];
}

// ---------------------------------------------------------------------------
// One-shot conversion of x (2048 blocks) + all weights (768 blocks) to bf16.
// ---------------------------------------------------------------------------
__global__ __launch_bounds__(256) void cvt_all(const void* __restrict__ x,
                                               const void* __restrict__ s0,
                                               const void* __restrict__ s1,
                                               const void* __restrict__ s2,
                                               const void* __restrict__ s3,
                                               bf16* __restrict__ xb,
                                               bf16* __restrict__ warena,
                                               const int* __restrict__ flag) {
  const bool f32in = (*flag == 0);
  const int b = blockIdx.x;
  if (b < 2048) {  // x: 8192*512 = 2048 * 2048 elems
    const size_t idx = ((size_t)b * 256 + threadIdx.x) * 8;
    *(bf16x8*)(xb + idx) = ld8(x, idx, f32in);
    return;
  }
  const int wb = b - 2048;
  const void* s;
  size_t doff;
  int lb;
  if (wb < 384)      { s = s0; doff = 0;        lb = wb; }
  else if (wb < 512) { s = s1; doff = 786432;   lb = wb - 384; }
  else if (wb < 640) { s = s2; doff = 1048576;  lb = wb - 512; }
  else               { s = s3; doff = 1310720;  lb = wb - 640; }
  const size_t idx = (size_t)lb * 2048 + threadIdx.x * 8;
  *(bf16x8*)(warena + doff + idx) = ld8(s, idx, f32in);
}

// ---------------------------------------------------------------------------
// GEMM v3: C[M,N] = A[M,512] @ W[N,512]^T + bias, optional ReLU. All-bf16.
// 64x64 tile (grid M/64 x N/64 -> 4-5 blocks/CU), BK=64, register-prefetch
// double-buffered LDS with ONE barrier per K-iter: next tile's global b128
// loads issue before compute, drain into ds_writes after the MFMAs -> memory
// latency overlaps compute (no more serial vmcnt(0) drain). XOR-swizzled LDS
// (R5-verified conflict-free). VGPR ~70: no spill risk (R6 lesson).
// ---------------------------------------------------------------------------
template <bool RELU>
__global__ __launch_bounds__(256) void gemm64(const bf16* __restrict__ A,
                                              const bf16* __restrict__ W,
                                              const void* __restrict__ bias,
                                              bf16* __restrict__ C, int N,
                                              const int* __restrict__ flag) {
  __shared__ __align__(16) bf16 As[2][64 * 64];
  __shared__ __align__(16) bf16 Ws[2][64 * 64];

  const bool f32in = (*flag == 0);

  const int t = threadIdx.x;
  const int lane = t & 63;
  const int wave = t >> 6;
  const int l16 = lane & 15;
  const int quad = lane >> 4;
  const int m0 = blockIdx.y * 64;
  const int n0 = blockIdx.x * 64;
  const int wm = (wave >> 1) * 32;
  const int wn = (wave & 1) * 32;

  // staging map: wave covers rows wave*16 + i*8 + rr (i<2), col block cb
  const int rr = lane >> 3;
  const int cb = (lane & 7) ^ rr;      // XOR swizzle (write side)
  const int sw = l16 & 7;              // read-side swizzle key
  const int arow = wave * 16 + rr;     // + i*8
  const int lslot = (wave * 16 + rr) * 64 + (lane & 7) * 8;

  f32x4 acc[2][2];
#pragma unroll
  for (int i = 0; i < 2; ++i)
#pragma unroll
    for (int j = 0; j < 2; ++j) acc[i][j] = (f32x4){0.f, 0.f, 0.f, 0.f};

  uint4 ra[2], rw[2];
#pragma unroll
  for (int i = 0; i < 2; ++i) {  // prologue: tile 0 -> regs
    ra[i] = *(const uint4*)&A[(size_t)(m0 + arow + i * 8) * K_DIM + cb * 8];
    rw[i] = *(const uint4*)&W[(size_t)(n0 + arow + i * 8) * K_DIM + cb * 8];
  }
#pragma unroll
  for (int i = 0; i < 2; ++i) {  // -> LDS[0]
    *(uint4*)&As[0][lslot + i * 8 * 64] = ra[i];
    *(uint4*)&Ws[0][lslot + i * 8 * 64] = rw[i];
  }

  for (int it = 0; it < K_DIM / 64; ++it) {
    const int cur = it & 1;
    const bool have_next = (it + 1 < K_DIM / 64);
    if (have_next) {  // issue next tile's global loads (in flight thru MFMAs)
      const int kt = (it + 1) * 64;
#pragma unroll
      for (int i = 0; i < 2; ++i) {
        ra[i] = *(const uint4*)&A[(size_t)(m0 + arow + i * 8) * K_DIM + kt + cb * 8];
        rw[i] = *(const uint4*)&W[(size_t)(n0 + arow + i * 8) * K_DIM + kt + cb * 8];
      }
    }
    __syncthreads();  // LDS[cur] fully staged by all waves
#pragma unroll
    for (int ks = 0; ks < 2; ++ks) {
      bf16x8 af[2], wf[2];
#pragma unroll
      for (int mt = 0; mt < 2; ++mt)
        af[mt] = *(const bf16x8*)&As[cur][(wm + mt * 16 + l16) * 64 +
                                          (((ks * 4 + quad) ^ sw) * 8)];
#pragma unroll
      for (int nt = 0; nt < 2; ++nt)
        wf[nt] = *(const bf16x8*)&Ws[cur][(wn + nt * 16 + l16) * 64 +
                                          (((ks * 4 + quad) ^ sw) * 8)];
#pragma unroll
      for (int mt = 0; mt < 2; ++mt)
#pragma unroll
        for (int nt = 0; nt < 2; ++nt)
          acc[mt][nt] = __builtin_amdgcn_mfma_f32_16x16x32_bf16(af[mt], wf[nt],
                                                                acc[mt][nt], 0, 0, 0);
    }
    if (have_next) {  // drain loads into LDS[cur^1]; next barrier protects
#pragma unroll
      for (int i = 0; i < 2; ++i) {
        *(uint4*)&As[cur ^ 1][lslot + i * 8 * 64] = ra[i];
        *(uint4*)&Ws[cur ^ 1][lslot + i * 8 * 64] = rw[i];
      }
    }
  }

#pragma unroll
  for (int nt = 0; nt < 2; ++nt) {
    const int n = n0 + wn + nt * 16 + l16;
    const float bv = ld1(bias, n, f32in);
#pragma unroll
    for (int mt = 0; mt < 2; ++mt) {
#pragma unroll
      for (int r = 0; r < 4; ++r) {
        const int m = m0 + wm + mt * 16 + quad * 4 + r;
        float v = acc[mt][nt][r] + bv;
        if (RELU) v = fmaxf(v, 0.f);
        C[(size_t)m * N + n] = (bf16)v;
      }
    }
  }
}

// ---------------------------------------------------------------------------
// Sliding-window attention: EXACT R5 body (55 us, VGPR 60, no spills) with
// only the XCD-swizzle block decode added. xcd = bid&7 selects the (b,h)
// pair so each XCD's L2 holds just 2 heads' K/V (~3 MB < 4 MB L2).
// NO K-register prefetch, NO launch_bounds cap (R6's spill regression).
// ---------------------------------------------------------------------------
__global__ __launch_bounds__(256) void attn_fwd(const bf16* __restrict__ qkv,
                                                bf16* __restrict__ ctx,
                                                const int* __restrict__ wptr) {
  __shared__ __align__(16) bf16 Vt[2][64][72];   // [buf][dh][key] (+8 pad)
  __shared__ __align__(16) bf16 Pbuf[4][16][72]; // per-wave [q][key] (+8 pad)

  const int t = threadIdx.x;
  const int lane = t & 63;
  const int wave = t >> 6;
  const int l16 = lane & 15;
  const int quad = lane >> 4;

  // XCD-aware decode: 1024 blocks = 8 xcd * (2 pairs * 64 qblks)
  const int bid = blockIdx.x;
  const int xcd = bid & 7;
  const int jj = bid >> 3;                 // 0..127
  const int pair = xcd * 2 + (jj >> 6);    // 0..15 = (b,h)
  const int qblk = jj & 63;
  const int h = pair & 7;
  const int b = pair >> 3;
  const int qbase = qblk * 64;
  int window = *wptr;
  if (window < 0) window = 0;
  if (window > S_LEN) window = S_LEN;
  const float scale = 0.125f;  // 1/sqrt(64)

  const int qrow = qbase + wave * 16 + l16;
  const bf16* qp = qkv + (size_t)(b * S_LEN + qrow) * QKV_LD + h * DHEAD;
  const bf16x8 qf0 = *(const bf16x8*)(qp + quad * 8);
  const bf16x8 qf1 = *(const bf16x8*)(qp + 32 + quad * 8);

  f32x4 o[4];
#pragma unroll
  for (int nt = 0; nt < 4; ++nt) o[nt] = (f32x4){0.f, 0.f, 0.f, 0.f};
  float lp[4] = {0.f, 0.f, 0.f, 0.f};

  int kstart = qbase - window;
  if (kstart < 0) kstart = 0;
  kstart &= ~63;
  int kend = qbase + 64 + window;
  if (kend > S_LEN) kend = S_LEN;
  const int niter = (kend - kstart + 63) >> 6;

  const int vk = (t & 31) * 2;
  const int vd = (t >> 5) * 8;
  const bf16* vbase = qkv + (size_t)(b * S_LEN) * QKV_LD + 2 * DMODEL + h * DHEAD + vd;
  const bf16* kbase = qkv + (size_t)(b * S_LEN) * QKV_LD + DMODEL + h * DHEAD;

  {  // prologue: stage V tile 0 into Vt[0]
    const bf16* p = vbase + (size_t)(kstart + vk) * QKV_LD;
    const bf16x8 va = *(const bf16x8*)p;
    const bf16x8 vb = *(const bf16x8*)(p + QKV_LD);
#pragma unroll
    for (int j = 0; j < 8; ++j) {
      bf16x2 pr; pr[0] = va[j]; pr[1] = vb[j];
      *(bf16x2*)&Vt[0][vd + j][vk] = pr;
    }
  }

  for (int it = 0; it < niter; ++it) {
    const int kt = kstart + it * 64;
    const int cur = it & 1;
    __syncthreads();

    bf16x8 na, nb;
    const bool have_next = (it + 1 < niter);
    if (have_next) {
      const bf16* p = vbase + (size_t)(kt + 64 + vk) * QKV_LD;
      na = *(const bf16x8*)p;
      nb = *(const bf16x8*)(p + QKV_LD);
    }

    f32x4 s[4];
#pragma unroll
    for (int t4 = 0; t4 < 4; ++t4) s[t4] = (f32x4){0.f, 0.f, 0.f, 0.f};
#pragma unroll
    for (int t4 = 0; t4 < 4; ++t4) {
      const bf16* kp = kbase + (size_t)(kt + t4 * 16 + l16) * QKV_LD;
      const bf16x8 k0 = *(const bf16x8*)(kp + quad * 8);
      const bf16x8 k1 = *(const bf16x8*)(kp + 32 + quad * 8);
      s[t4] = __builtin_amdgcn_mfma_f32_16x16x32_bf16(qf0, k0, s[t4], 0, 0, 0);
      s[t4] = __builtin_amdgcn_mfma_f32_16x16x32_bf16(qf1, k1, s[t4], 0, 0, 0);
    }

#pragma unroll
    for (int r = 0; r < 4; ++r) {
      const int q = qbase + wave * 16 + quad * 4 + r;
      const int lo = q - window, hi = q + window;
      float psum = 0.f;
#pragma unroll
      for (int t4 = 0; t4 < 4; ++t4) {
        const int key = kt + t4 * 16 + l16;
        const float p = (key >= lo && key <= hi) ? __expf(s[t4][r] * scale) : 0.f;
        psum += p;
        Pbuf[wave][quad * 4 + r][t4 * 16 + l16] = (bf16)p;
      }
      lp[r] += psum;
    }

    const bf16x8 pf0 = *(const bf16x8*)&Pbuf[wave][l16][quad * 8];
    const bf16x8 pf1 = *(const bf16x8*)&Pbuf[wave][l16][32 + quad * 8];
#pragma unroll
    for (int nt = 0; nt < 4; ++nt) {
      const bf16x8 v0 = *(const bf16x8*)&Vt[cur][nt * 16 + l16][quad * 8];
      const bf16x8 v1 = *(const bf16x8*)&Vt[cur][nt * 16 + l16][32 + quad * 8];
      o[nt] = __builtin_amdgcn_mfma_f32_16x16x32_bf16(pf0, v0, o[nt], 0, 0, 0);
      o[nt] = __builtin_amdgcn_mfma_f32_16x16x32_bf16(pf1, v1, o[nt], 0, 0, 0);
    }

    if (have_next) {
#pragma unroll
      for (int j = 0; j < 8; ++j) {
        bf16x2 pr; pr[0] = na[j]; pr[1] = nb[j];
        *(bf16x2*)&Vt[cur ^ 1][vd + j][vk] = pr;
      }
    }
  }

#pragma unroll
  for (int r = 0; r < 4; ++r) {
#pragma unroll
    for (int off = 1; off < 16; off <<= 1) lp[r] += __shfl_xor(lp[r], off);
    const float inv = (lp[r] > 0.f) ? (1.0f / lp[r]) : 0.f;
    const int q = qbase + wave * 16 + quad * 4 + r;
#pragma unroll
    for (int nt = 0; nt < 4; ++nt) {
      ctx[(size_t)(b * S_LEN + q) * DMODEL + h * DHEAD + nt * 16 + l16] =
          (bf16)(o[nt][r] * inv);
    }
  }
}

// ---------------------------------------------------------------------------
// Fused residual + LayerNorm (R3-verified). One wave per row, 4 rows/block.
// ---------------------------------------------------------------------------
template <bool A_RAW, bool OUT_RAW>
__global__ __launch_bounds__(256) void ln_fused(const void* __restrict__ a,
                                                const bf16* __restrict__ bres,
                                                const void* __restrict__ g,
                                                const void* __restrict__ be,
                                                void* __restrict__ out,
                                                const int* __restrict__ flag) {
  const bool f32in = (*flag == 0);
  const int row = blockIdx.x * 4 + (threadIdx.x >> 6);
  const int lane = threadIdx.x & 63;
  const size_t base = (size_t)row * DMODEL + lane * 8;
  const bf16x8 va = ld8(a, base, A_RAW && f32in);
  const bf16x8 vb = *(const bf16x8*)(bres + base);
  float v[8], s = 0.f, s2 = 0.f;
#pragma unroll
  for (int j = 0; j < 8; ++j) {
    v[j] = (float)va[j] + (float)vb[j];
    s += v[j];
    s2 += v[j] * v[j];
  }
#pragma unroll
  for (int off = 1; off < 64; off <<= 1) {
    s += __shfl_xor(s, off);
    s2 += __shfl_xor(s2, off);
  }
  const float mean = s * (1.0f / DMODEL);
  float var = s2 * (1.0f / DMODEL) - mean * mean;
  if (var < 0.f) var = 0.f;
  const float rstd = rsqrtf(var + 1e-5f);
  const bf16x8 gv = ld8(g, lane * 8, f32in);
  const bf16x8 bev = ld8(be, lane * 8, f32in);
  float ov[8];
#pragma unroll
  for (int j = 0; j < 8; ++j)
    ov[j] = (v[j] - mean) * rstd * (float)gv[j] + (float)bev[j];
  if (OUT_RAW && f32in) {
    float4 o0 = {ov[0], ov[1], ov[2], ov[3]};
    float4 o1 = {ov[4], ov[5], ov[6], ov[7]};
    *(float4*)((float*)out + base) = o0;
    *(float4*)((float*)out + base + 4) = o1;
  } else {
    bf16x8 ob;
#pragma unroll
    for (int j = 0; j < 8; ++j) ob[j] = (bf16)ov[j];
    *(bf16x8*)((bf16*)out + base) = ob;
  }
}

// ---------------------------------------------------------------------------
extern "C" void kernel_launch(void* const* d_in, const int* in_sizes, int n_in,
                              void* d_out, int out_size, void* d_ws, size_t ws_size,
                              hipStream_t stream) {
  const void* x          = d_in[0];
  const void* in_proj_w  = d_in[1];
  const void* in_proj_b  = d_in[2];
  const void* out_proj_w = d_in[3];
  const void* out_proj_b = d_in[4];
  const void* ln1_g      = d_in[5];
  const void* ln1_b      = d_in[6];
  const void* ln2_g      = d_in[7];
  const void* ln2_b      = d_in[8];
  const void* w1         = d_in[9];
  const void* b1         = d_in[10];
  const void* w2         = d_in[11];
  const void* b2         = d_in[12];
  const int*  wptr       = (const int*)d_in[13];

  // Workspace (28.3 MB): flag | bf16 weight arena (3 MB) | big region:
  // qkv [steps 1-2] then h / a1 / attn_out(mlp). d_out doubles as xb then ctx.
  char* ws = (char*)d_ws;
  int* flag = (int*)ws;
  bf16* warena = (bf16*)(ws + 256);
  bf16* wq = warena;
  bf16* wo = warena + 786432;
  bf16* w1b = warena + 1048576;
  bf16* w2b = warena + 1310720;
  char* big = ws + 256 + 3145728;
  bf16* qkv      = (bf16*)big;
  bf16* h        = (bf16*)big;
  bf16* a1       = (bf16*)(big + 8388608);
  bf16* attn_out = (bf16*)(big + 16777216);
  bf16* mlp      = attn_out;
  bf16* xb       = (bf16*)d_out;
  bf16* ctx      = (bf16*)d_out;

  detect_dtype<<<1, 64, 0, stream>>>((const unsigned int*)x, flag);
  cvt_all<<<2816, 256, 0, stream>>>(x, in_proj_w, out_proj_w, w1, w2, xb, warena, flag);
  // 1. qkv = xb @ in_proj_w^T + b   [M=8192, N=1536]
  gemm64<false><<<dim3(QKV_LD / 64, M_ROWS / 64), 256, 0, stream>>>(
      xb, wq, in_proj_b, qkv, QKV_LD, flag);
  // 2. sliding-window attention -> ctx (xb dead from here)
  attn_fwd<<<dim3(BATCH * NHEAD * (S_LEN / 64)), 256, 0, stream>>>(qkv, ctx, wptr);
  // 3. attn_out = ctx @ out_proj_w^T + b
  gemm64<false><<<dim3(DMODEL / 64, M_ROWS / 64), 256, 0, stream>>>(
      ctx, wo, out_proj_b, attn_out, DMODEL, flag);
  // 4. h = LN(x + attn_out)   (reads raw x: dual-dtype)
  ln_fused<true, false><<<dim3(M_ROWS / 4), 256, 0, stream>>>(
      x, attn_out, ln1_g, ln1_b, h, flag);
  // 5. a1 = relu(h @ w1^T + b1)
  gemm64<true><<<dim3(DMODEL / 64, M_ROWS / 64), 256, 0, stream>>>(
      h, w1b, b1, a1, DMODEL, flag);
  // 6. mlp = a1 @ w2^T + b2
  gemm64<false><<<dim3(DMODEL / 64, M_ROWS / 64), 256, 0, stream>>>(
      a1, w2b, b2, mlp, DMODEL, flag);
  // 7. out = LN(h + mlp)
  ln_fused<false, true><<<dim3(M_ROWS / 4), 256, 0, stream>>>(
      h, mlp, ln2_g, ln2_b, d_out, flag);
}

// Round 8
// 226.435 us; speedup vs baseline: 1.5843x; 1.5843x over previous
//
#include <hip/hip_runtime.h>

typedef __bf16 bf16;
typedef __bf16 bf16x2 __attribute__((ext_vector_type(2)));
typedef __bf16 bf16x8 __attribute__((ext_vector_type(8)));
typedef float f32x4 __attribute__((ext_vector_type(4)));

#define S_LEN 4096
#define DMODEL 512
#define NHEAD 8
#define DHEAD 64
#define BATCH 2
#define M_ROWS (BATCH * S_LEN)   // 8192
#define K_DIM 512
#define QKV_LD 1536

// ---------------------------------------------------------------------------
// async global->LDS, 16 B per lane (wave-uniform LDS base + 16*lane scatter).
// ---------------------------------------------------------------------------
__device__ __forceinline__ void async16(void* lds, const void* g) {
  __builtin_amdgcn_global_load_lds(
      (const __attribute__((address_space(1))) unsigned int*)g,
      (__attribute__((address_space(3))) unsigned int*)lds, 16, 0, 0);
}

// ---------------------------------------------------------------------------
// Dtype detection (R3-verified): flag = 1 if bf16 inputs, 0 if f32.
// ---------------------------------------------------------------------------
__global__ void detect_dtype(const unsigned int* __restrict__ x,
                             int* __restrict__ flag) {
  const int lane = threadIdx.x;  // 64 lanes
  int cnt = 0;
#pragma unroll
  for (int i = 0; i < 16; ++i) {
    const unsigned int w = x[lane * 16 + i];
    const unsigned int e = (w >> 7) & 0xFFu;
    cnt += (e >= 100u && e <= 140u) ? 1 : 0;
  }
#pragma unroll
  for (int off = 1; off < 64; off <<= 1) cnt += __shfl_xor(cnt, off);
  if (lane == 0) *flag = (cnt >= 700) ? 1 : 0;
}

__device__ __forceinline__ bf16x8 ld8(const void* p, size_t e, bool asF32) {
  if (asF32) {
    const float* q = (const float*)p + e;
    const float4 a = *(const float4*)q;
    const float4 b = *(const float4*)(q + 4);
    bf16x8 r;
    r[0] = (bf16)a.x; r[1] = (bf16)a.y; r[2] = (bf16)a.z; r[3] = (bf16)a.w;
    r[4] = (bf16)b.x; r[5] = (bf16)b.y; r[6] = (bf16)b.z; r[7] = (bf16)b.w;
    return r;
  }
  return *(const bf16x8*)((const bf16*)p + e);
}

__device__ __forceinline__ float ld1(const void* p, size_t e, bool asF32) {
  return asF32 ? ((const float*)p)[e] : (float)((const bf16*)p)[e];
}

// ---------------------------------------------------------------------------
// One-shot conversion of x (2048 blocks) + all weights (768 blocks) to bf16.
// ---------------------------------------------------------------------------
__global__ __launch_bounds__(256) void cvt_all(const void* __restrict__ x,
                                               const void* __restrict__ s0,
                                               const void* __restrict__ s1,
                                               const void* __restrict__ s2,
                                               const void* __restrict__ s3,
                                               bf16* __restrict__ xb,
                                               bf16* __restrict__ warena,
                                               const int* __restrict__ flag) {
  const bool f32in = (*flag == 0);
  const int b = blockIdx.x;
  if (b < 2048) {  // x: 8192*512 = 2048 * 2048 elems
    const size_t idx = ((size_t)b * 256 + threadIdx.x) * 8;
    *(bf16x8*)(xb + idx) = ld8(x, idx, f32in);
    return;
  }
  const int wb = b - 2048;
  const void* s;
  size_t doff;
  int lb;
  if (wb < 384)      { s = s0; doff = 0;        lb = wb; }
  else if (wb < 512) { s = s1; doff = 786432;   lb = wb - 384; }
  else if (wb < 640) { s = s2; doff = 1048576;  lb = wb - 512; }
  else               { s = s3; doff = 1310720;  lb = wb - 640; }
  const size_t idx = (size_t)lb * 2048 + threadIdx.x * 8;
  *(bf16x8*)(warena + doff + idx) = ld8(s, idx, f32in);
}

// ---------------------------------------------------------------------------
// GEMM (exact R5 structure — measured good: no write amplification, async16
// staging, XOR-swizzled LDS conflict-free): C[M,N] = A[M,512] @ W[N,512]^T
// + bias, optional ReLU. M-tile 128, N-tile BN (128|64).
// ---------------------------------------------------------------------------
template <int BN, bool RELU>
__global__ __launch_bounds__(256) void gemm_bt(const bf16* __restrict__ A,
                                               const bf16* __restrict__ W,
                                               const void* __restrict__ bias,
                                               bf16* __restrict__ C, int N,
                                               const int* __restrict__ flag) {
  __shared__ __align__(16) bf16 As[128 * 64];
  __shared__ __align__(16) bf16 Ws[BN * 64];

  const bool f32in = (*flag == 0);

  const int t = threadIdx.x;
  const int lane = t & 63;
  const int wave = t >> 6;
  constexpr int MT = (BN == 128) ? 4 : 2;
  const int wm = (BN == 128) ? (wave >> 1) * 64 : wave * 32;
  const int wn = (BN == 128) ? (wave & 1) * 64 : 0;
  const int l16 = lane & 15;
  const int quad = lane >> 4;
  const int m0 = blockIdx.y * 128;
  const int n0 = blockIdx.x * BN;

  const int rr = lane >> 3;
  const int cb = (lane & 7) ^ rr;      // XOR swizzle (write side)
  const int sw = l16 & 7;              // read-side swizzle key

  f32x4 acc[MT][4];
#pragma unroll
  for (int i = 0; i < MT; ++i)
#pragma unroll
    for (int j = 0; j < 4; ++j) acc[i][j] = (f32x4){0.f, 0.f, 0.f, 0.f};

  for (int kt = 0; kt < K_DIM; kt += 64) {
    __syncthreads();
#pragma unroll
    for (int i = 0; i < 4; ++i) {
      const int r0 = wave * 32 + i * 8;
      async16(&As[r0 * 64], &A[(size_t)(m0 + r0 + rr) * K_DIM + kt + cb * 8]);
    }
#pragma unroll
    for (int i = 0; i < BN / 32; ++i) {
      const int r0 = wave * (BN / 4) + i * 8;
      async16(&Ws[r0 * 64], &W[(size_t)(n0 + r0 + rr) * K_DIM + kt + cb * 8]);
    }
    __syncthreads();
#pragma unroll
    for (int ks = 0; ks < 2; ++ks) {
      bf16x8 af[MT], wf[4];
#pragma unroll
      for (int mt = 0; mt < MT; ++mt)
        af[mt] = *(const bf16x8*)&As[(wm + mt * 16 + l16) * 64 +
                                     (((ks * 4 + quad) ^ sw) * 8)];
#pragma unroll
      for (int nt = 0; nt < 4; ++nt)
        wf[nt] = *(const bf16x8*)&Ws[(wn + nt * 16 + l16) * 64 +
                                     (((ks * 4 + quad) ^ sw) * 8)];
#pragma unroll
      for (int mt = 0; mt < MT; ++mt)
#pragma unroll
        for (int nt = 0; nt < 4; ++nt)
          acc[mt][nt] = __builtin_amdgcn_mfma_f32_16x16x32_bf16(af[mt], wf[nt],
                                                                acc[mt][nt], 0, 0, 0);
    }
  }

#pragma unroll
  for (int nt = 0; nt < 4; ++nt) {
    const int n = n0 + wn + nt * 16 + l16;
    const float bv = ld1(bias, n, f32in);
#pragma unroll
    for (int mt = 0; mt < MT; ++mt) {
#pragma unroll
      for (int r = 0; r < 4; ++r) {
        const int m = m0 + wm + mt * 16 + quad * 4 + r;
        float v = acc[mt][nt][r] + bv;
        if (RELU) v = fmaxf(v, 0.f);
        C[(size_t)m * N + n] = (bf16)v;
      }
    }
  }
}

// ---------------------------------------------------------------------------
// Sliding-window attention: R5 body (55 us, VGPR 60, no spills) + XCD
// swizzle only. xcd = bid&7 selects the (b,h) pair so each XCD's L2 holds
// just 2 heads' K/V (~3 MB < 4 MB L2) -> K/V re-reads become L2 hits.
// ---------------------------------------------------------------------------
__global__ __launch_bounds__(256) void attn_fwd(const bf16* __restrict__ qkv,
                                                bf16* __restrict__ ctx,
                                                const int* __restrict__ wptr) {
  __shared__ __align__(16) bf16 Vt[2][64][72];   // [buf][dh][key] (+8 pad)
  __shared__ __align__(16) bf16 Pbuf[4][16][72]; // per-wave [q][key] (+8 pad)

  const int t = threadIdx.x;
  const int lane = t & 63;
  const int wave = t >> 6;
  const int l16 = lane & 15;
  const int quad = lane >> 4;

  // XCD-aware decode: 1024 blocks = 8 xcd * (2 pairs * 64 qblks)
  const int bid = blockIdx.x;
  const int xcd = bid & 7;
  const int jj = bid >> 3;                 // 0..127
  const int pair = xcd * 2 + (jj >> 6);    // 0..15 = (b,h)
  const int qblk = jj & 63;
  const int h = pair & 7;
  const int b = pair >> 3;
  const int qbase = qblk * 64;
  int window = *wptr;
  if (window < 0) window = 0;
  if (window > S_LEN) window = S_LEN;
  const float scale = 0.125f;  // 1/sqrt(64)

  const int qrow = qbase + wave * 16 + l16;
  const bf16* qp = qkv + (size_t)(b * S_LEN + qrow) * QKV_LD + h * DHEAD;
  const bf16x8 qf0 = *(const bf16x8*)(qp + quad * 8);
  const bf16x8 qf1 = *(const bf16x8*)(qp + 32 + quad * 8);

  f32x4 o[4];
#pragma unroll
  for (int nt = 0; nt < 4; ++nt) o[nt] = (f32x4){0.f, 0.f, 0.f, 0.f};
  float lp[4] = {0.f, 0.f, 0.f, 0.f};

  int kstart = qbase - window;
  if (kstart < 0) kstart = 0;
  kstart &= ~63;
  int kend = qbase + 64 + window;
  if (kend > S_LEN) kend = S_LEN;
  const int niter = (kend - kstart + 63) >> 6;

  const int vk = (t & 31) * 2;
  const int vd = (t >> 5) * 8;
  const bf16* vbase = qkv + (size_t)(b * S_LEN) * QKV_LD + 2 * DMODEL + h * DHEAD + vd;
  const bf16* kbase = qkv + (size_t)(b * S_LEN) * QKV_LD + DMODEL + h * DHEAD;

  {  // prologue: stage V tile 0 into Vt[0]
    const bf16* p = vbase + (size_t)(kstart + vk) * QKV_LD;
    const bf16x8 va = *(const bf16x8*)p;
    const bf16x8 vb = *(const bf16x8*)(p + QKV_LD);
#pragma unroll
    for (int j = 0; j < 8; ++j) {
      bf16x2 pr; pr[0] = va[j]; pr[1] = vb[j];
      *(bf16x2*)&Vt[0][vd + j][vk] = pr;
    }
  }

  for (int it = 0; it < niter; ++it) {
    const int kt = kstart + it * 64;
    const int cur = it & 1;
    __syncthreads();

    bf16x8 na, nb;
    const bool have_next = (it + 1 < niter);
    if (have_next) {
      const bf16* p = vbase + (size_t)(kt + 64 + vk) * QKV_LD;
      na = *(const bf16x8*)p;
      nb = *(const bf16x8*)(p + QKV_LD);
    }

    f32x4 s[4];
#pragma unroll
    for (int t4 = 0; t4 < 4; ++t4) s[t4] = (f32x4){0.f, 0.f, 0.f, 0.f};
#pragma unroll
    for (int t4 = 0; t4 < 4; ++t4) {
      const bf16* kp = kbase + (size_t)(kt + t4 * 16 + l16) * QKV_LD;
      const bf16x8 k0 = *(const bf16x8*)(kp + quad * 8);
      const bf16x8 k1 = *(const bf16x8*)(kp + 32 + quad * 8);
      s[t4] = __builtin_amdgcn_mfma_f32_16x16x32_bf16(qf0, k0, s[t4], 0, 0, 0);
      s[t4] = __builtin_amdgcn_mfma_f32_16x16x32_bf16(qf1, k1, s[t4], 0, 0, 0);
    }

#pragma unroll
    for (int r = 0; r < 4; ++r) {
      const int q = qbase + wave * 16 + quad * 4 + r;
      const int lo = q - window, hi = q + window;
      float psum = 0.f;
#pragma unroll
      for (int t4 = 0; t4 < 4; ++t4) {
        const int key = kt + t4 * 16 + l16;
        const float p = (key >= lo && key <= hi) ? __expf(s[t4][r] * scale) : 0.f;
        psum += p;
        Pbuf[wave][quad * 4 + r][t4 * 16 + l16] = (bf16)p;
      }
      lp[r] += psum;
    }

    const bf16x8 pf0 = *(const bf16x8*)&Pbuf[wave][l16][quad * 8];
    const bf16x8 pf1 = *(const bf16x8*)&Pbuf[wave][l16][32 + quad * 8];
#pragma unroll
    for (int nt = 0; nt < 4; ++nt) {
      const bf16x8 v0 = *(const bf16x8*)&Vt[cur][nt * 16 + l16][quad * 8];
      const bf16x8 v1 = *(const bf16x8*)&Vt[cur][nt * 16 + l16][32 + quad * 8];
      o[nt] = __builtin_amdgcn_mfma_f32_16x16x32_bf16(pf0, v0, o[nt], 0, 0, 0);
      o[nt] = __builtin_amdgcn_mfma_f32_16x16x32_bf16(pf1, v1, o[nt], 0, 0, 0);
    }

    if (have_next) {
#pragma unroll
      for (int j = 0; j < 8; ++j) {
        bf16x2 pr; pr[0] = na[j]; pr[1] = nb[j];
        *(bf16x2*)&Vt[cur ^ 1][vd + j][vk] = pr;
      }
    }
  }

#pragma unroll
  for (int r = 0; r < 4; ++r) {
#pragma unroll
    for (int off = 1; off < 16; off <<= 1) lp[r] += __shfl_xor(lp[r], off);
    const float inv = (lp[r] > 0.f) ? (1.0f / lp[r]) : 0.f;
    const int q = qbase + wave * 16 + quad * 4 + r;
#pragma unroll
    for (int nt = 0; nt < 4; ++nt) {
      ctx[(size_t)(b * S_LEN + q) * DMODEL + h * DHEAD + nt * 16 + l16] =
          (bf16)(o[nt][r] * inv);
    }
  }
}

// ---------------------------------------------------------------------------
// Fused residual + LayerNorm (R3-verified). One wave per row, 4 rows/block.
// ---------------------------------------------------------------------------
template <bool A_RAW, bool OUT_RAW>
__global__ __launch_bounds__(256) void ln_fused(const void* __restrict__ a,
                                                const bf16* __restrict__ bres,
                                                const void* __restrict__ g,
                                                const void* __restrict__ be,
                                                void* __restrict__ out,
                                                const int* __restrict__ flag) {
  const bool f32in = (*flag == 0);
  const int row = blockIdx.x * 4 + (threadIdx.x >> 6);
  const int lane = threadIdx.x & 63;
  const size_t base = (size_t)row * DMODEL + lane * 8;
  const bf16x8 va = ld8(a, base, A_RAW && f32in);
  const bf16x8 vb = *(const bf16x8*)(bres + base);
  float v[8], s = 0.f, s2 = 0.f;
#pragma unroll
  for (int j = 0; j < 8; ++j) {
    v[j] = (float)va[j] + (float)vb[j];
    s += v[j];
    s2 += v[j] * v[j];
  }
#pragma unroll
  for (int off = 1; off < 64; off <<= 1) {
    s += __shfl_xor(s, off);
    s2 += __shfl_xor(s2, off);
  }
  const float mean = s * (1.0f / DMODEL);
  float var = s2 * (1.0f / DMODEL) - mean * mean;
  if (var < 0.f) var = 0.f;
  const float rstd = rsqrtf(var + 1e-5f);
  const bf16x8 gv = ld8(g, lane * 8, f32in);
  const bf16x8 bev = ld8(be, lane * 8, f32in);
  float ov[8];
#pragma unroll
  for (int j = 0; j < 8; ++j)
    ov[j] = (v[j] - mean) * rstd * (float)gv[j] + (float)bev[j];
  if (OUT_RAW && f32in) {
    float4 o0 = {ov[0], ov[1], ov[2], ov[3]};
    float4 o1 = {ov[4], ov[5], ov[6], ov[7]};
    *(float4*)((float*)out + base) = o0;
    *(float4*)((float*)out + base + 4) = o1;
  } else {
    bf16x8 ob;
#pragma unroll
    for (int j = 0; j < 8; ++j) ob[j] = (bf16)ov[j];
    *(bf16x8*)((bf16*)out + base) = ob;
  }
}

// ---------------------------------------------------------------------------
extern "C" void kernel_launch(void* const* d_in, const int* in_sizes, int n_in,
                              void* d_out, int out_size, void* d_ws, size_t ws_size,
                              hipStream_t stream) {
  const void* x          = d_in[0];
  const void* in_proj_w  = d_in[1];
  const void* in_proj_b  = d_in[2];
  const void* out_proj_w = d_in[3];
  const void* out_proj_b = d_in[4];
  const void* ln1_g      = d_in[5];
  const void* ln1_b      = d_in[6];
  const void* ln2_g      = d_in[7];
  const void* ln2_b      = d_in[8];
  const void* w1         = d_in[9];
  const void* b1         = d_in[10];
  const void* w2         = d_in[11];
  const void* b2         = d_in[12];
  const int*  wptr       = (const int*)d_in[13];

  // Workspace (28.3 MB): flag | bf16 weight arena (3 MB) | big region:
  // qkv [steps 1-2] then h / a1 / attn_out(mlp). d_out doubles as xb then ctx.
  char* ws = (char*)d_ws;
  int* flag = (int*)ws;
  bf16* warena = (bf16*)(ws + 256);
  bf16* wq = warena;
  bf16* wo = warena + 786432;
  bf16* w1b = warena + 1048576;
  bf16* w2b = warena + 1310720;
  char* big = ws + 256 + 3145728;
  bf16* qkv      = (bf16*)big;
  bf16* h        = (bf16*)big;
  bf16* a1       = (bf16*)(big + 8388608);
  bf16* attn_out = (bf16*)(big + 16777216);
  bf16* mlp      = attn_out;
  bf16* xb       = (bf16*)d_out;
  bf16* ctx      = (bf16*)d_out;

  detect_dtype<<<1, 64, 0, stream>>>((const unsigned int*)x, flag);
  cvt_all<<<2816, 256, 0, stream>>>(x, in_proj_w, out_proj_w, w1, w2, xb, warena, flag);
  // 1. qkv = xb @ in_proj_w^T + b   [M=8192, N=1536]
  gemm_bt<128, false><<<dim3(QKV_LD / 128, M_ROWS / 128), 256, 0, stream>>>(
      xb, wq, in_proj_b, qkv, QKV_LD, flag);
  // 2. sliding-window attention -> ctx (xb dead from here)
  attn_fwd<<<dim3(BATCH * NHEAD * (S_LEN / 64)), 256, 0, stream>>>(qkv, ctx, wptr);
  // 3. attn_out = ctx @ out_proj_w^T + b
  gemm_bt<64, false><<<dim3(DMODEL / 64, M_ROWS / 128), 256, 0, stream>>>(
      ctx, wo, out_proj_b, attn_out, DMODEL, flag);
  // 4. h = LN(x + attn_out)   (reads raw x: dual-dtype)
  ln_fused<true, false><<<dim3(M_ROWS / 4), 256, 0, stream>>>(
      x, attn_out, ln1_g, ln1_b, h, flag);
  // 5. a1 = relu(h @ w1^T + b1)
  gemm_bt<64, true><<<dim3(DMODEL / 64, M_ROWS / 128), 256, 0, stream>>>(
      h, w1b, b1, a1, DMODEL, flag);
  // 6. mlp = a1 @ w2^T + b2
  gemm_bt<64, false><<<dim3(DMODEL / 64, M_ROWS / 128), 256, 0, stream>>>(
      a1, w2b, b2, mlp, DMODEL, flag);
  // 7. out = LN(h + mlp)
  ln_fused<false, true><<<dim3(M_ROWS / 4), 256, 0, stream>>>(
      h, mlp, ln2_g, ln2_b, d_out, flag);
}

// Round 9
// 221.590 us; speedup vs baseline: 1.6190x; 1.0219x over previous
//
#include <hip/hip_runtime.h>

typedef __bf16 bf16;
typedef __bf16 bf16x2 __attribute__((ext_vector_type(2)));
typedef __bf16 bf16x8 __attribute__((ext_vector_type(8)));
typedef float f32x4 __attribute__((ext_vector_type(4)));

#define S_LEN 4096
#define DMODEL 512
#define NHEAD 8
#define DHEAD 64
#define BATCH 2
#define M_ROWS (BATCH * S_LEN)   // 8192
#define K_DIM 512
#define QKV_LD 1536

// ---------------------------------------------------------------------------
// async global->LDS, 16 B per lane (wave-uniform LDS base + 16*lane scatter).
// ---------------------------------------------------------------------------
__device__ __forceinline__ void async16(void* lds, const void* g) {
  __builtin_amdgcn_global_load_lds(
      (const __attribute__((address_space(1))) unsigned int*)g,
      (__attribute__((address_space(3))) unsigned int*)lds, 16, 0, 0);
}

// ---------------------------------------------------------------------------
// Dtype detection (R3-verified): flag = 1 if bf16 inputs, 0 if f32.
// ---------------------------------------------------------------------------
__global__ void detect_dtype(const unsigned int* __restrict__ x,
                             int* __restrict__ flag) {
  const int lane = threadIdx.x;  // 64 lanes
  int cnt = 0;
#pragma unroll
  for (int i = 0; i < 16; ++i) {
    const unsigned int w = x[lane * 16 + i];
    const unsigned int e = (w >> 7) & 0xFFu;
    cnt += (e >= 100u && e <= 140u) ? 1 : 0;
  }
#pragma unroll
  for (int off = 1; off < 64; off <<= 1) cnt += __shfl_xor(cnt, off);
  if (lane == 0) *flag = (cnt >= 700) ? 1 : 0;
}

__device__ __forceinline__ bf16x8 ld8(const void* p, size_t e, bool asF32) {
  if (asF32) {
    const float* q = (const float*)p + e;
    const float4 a = *(const float4*)q;
    const float4 b = *(const float4*)(q + 4);
    bf16x8 r;
    r[0] = (bf16)a.x; r[1] = (bf16)a.y; r[2] = (bf16)a.z; r[3] = (bf16)a.w;
    r[4] = (bf16)b.x; r[5] = (bf16)b.y; r[6] = (bf16)b.z; r[7] = (bf16)b.w;
    return r;
  }
  return *(const bf16x8*)((const bf16*)p + e);
}

__device__ __forceinline__ float ld1(const void* p, size_t e, bool asF32) {
  return asF32 ? ((const float*)p)[e] : (float)((const bf16*)p)[e];
}

// ---------------------------------------------------------------------------
// One-shot conversion of x (2048 blocks) + all weights (768 blocks) to bf16.
// ---------------------------------------------------------------------------
__global__ __launch_bounds__(256) void cvt_all(const void* __restrict__ x,
                                               const void* __restrict__ s0,
                                               const void* __restrict__ s1,
                                               const void* __restrict__ s2,
                                               const void* __restrict__ s3,
                                               bf16* __restrict__ xb,
                                               bf16* __restrict__ warena,
                                               const int* __restrict__ flag) {
  const bool f32in = (*flag == 0);
  const int b = blockIdx.x;
  if (b < 2048) {  // x: 8192*512 = 2048 * 2048 elems
    const size_t idx = ((size_t)b * 256 + threadIdx.x) * 8;
    *(bf16x8*)(xb + idx) = ld8(x, idx, f32in);
    return;
  }
  const int wb = b - 2048;
  const void* s;
  size_t doff;
  int lb;
  if (wb < 384)      { s = s0; doff = 0;        lb = wb; }
  else if (wb < 512) { s = s1; doff = 786432;   lb = wb - 384; }
  else if (wb < 640) { s = s2; doff = 1048576;  lb = wb - 512; }
  else               { s = s3; doff = 1310720;  lb = wb - 640; }
  const size_t idx = (size_t)lb * 2048 + threadIdx.x * 8;
  *(bf16x8*)(warena + doff + idx) = ld8(s, idx, f32in);
}

// ---------------------------------------------------------------------------
// GEMM (R5/R8-proven body + XCD-swizzled 1D grid): C[M, NMAT] =
// A[M,512] @ W[NMAT,512]^T + bias, optional ReLU.
// Grid = (NMAT/BN) * 64 blocks, 1D. xcd = bid&7 owns 8 contiguous m-bands
// and sweeps all n for them -> the A band (~1 MB) and W (<=1.5 MB) stay
// resident in that XCD's 4 MB L2, so the per-K-iter vmcnt(0) drain waits on
// L2 (~200 cyc) instead of HBM (~900 cyc). R4 arithmetic: old n-fastest
// order re-fetched A from 8 XCDs = 64*8*0.131 MB ~ 67 MB (measured 69).
// ---------------------------------------------------------------------------
template <int NMAT, int BN, bool RELU>
__global__ __launch_bounds__(256) void gemm_bt(const bf16* __restrict__ A,
                                               const bf16* __restrict__ W,
                                               const void* __restrict__ bias,
                                               bf16* __restrict__ C,
                                               const int* __restrict__ flag) {
  __shared__ __align__(16) bf16 As[128 * 64];
  __shared__ __align__(16) bf16 Ws[BN * 64];

  const bool f32in = (*flag == 0);

  const int t = threadIdx.x;
  const int lane = t & 63;
  const int wave = t >> 6;
  constexpr int MT = (BN == 128) ? 4 : 2;
  const int wm = (BN == 128) ? (wave >> 1) * 64 : wave * 32;
  const int wn = (BN == 128) ? (wave & 1) * 64 : 0;
  const int l16 = lane & 15;
  const int quad = lane >> 4;

  // XCD-aware tile decode (compile-time divisors -> magic-mul)
  constexpr int NB = NMAT / BN;        // n-blocks per m-band
  constexpr int MPX = (M_ROWS / 128) / 8;  // m-bands per XCD = 8
  const int bid = blockIdx.x;
  const int xcd = bid & 7;
  const int r = bid >> 3;
  const int m0 = (xcd * MPX + r / NB) * 128;
  const int n0 = (r % NB) * BN;

  const int rr = lane >> 3;
  const int cb = (lane & 7) ^ rr;      // XOR swizzle (write side)
  const int sw = l16 & 7;              // read-side swizzle key

  f32x4 acc[MT][4];
#pragma unroll
  for (int i = 0; i < MT; ++i)
#pragma unroll
    for (int j = 0; j < 4; ++j) acc[i][j] = (f32x4){0.f, 0.f, 0.f, 0.f};

  for (int kt = 0; kt < K_DIM; kt += 64) {
    __syncthreads();
#pragma unroll
    for (int i = 0; i < 4; ++i) {
      const int r0 = wave * 32 + i * 8;
      async16(&As[r0 * 64], &A[(size_t)(m0 + r0 + rr) * K_DIM + kt + cb * 8]);
    }
#pragma unroll
    for (int i = 0; i < BN / 32; ++i) {
      const int r0 = wave * (BN / 4) + i * 8;
      async16(&Ws[r0 * 64], &W[(size_t)(n0 + r0 + rr) * K_DIM + kt + cb * 8]);
    }
    __syncthreads();
#pragma unroll
    for (int ks = 0; ks < 2; ++ks) {
      bf16x8 af[MT], wf[4];
#pragma unroll
      for (int mt = 0; mt < MT; ++mt)
        af[mt] = *(const bf16x8*)&As[(wm + mt * 16 + l16) * 64 +
                                     (((ks * 4 + quad) ^ sw) * 8)];
#pragma unroll
      for (int nt = 0; nt < 4; ++nt)
        wf[nt] = *(const bf16x8*)&Ws[(wn + nt * 16 + l16) * 64 +
                                     (((ks * 4 + quad) ^ sw) * 8)];
#pragma unroll
      for (int mt = 0; mt < MT; ++mt)
#pragma unroll
        for (int nt = 0; nt < 4; ++nt)
          acc[mt][nt] = __builtin_amdgcn_mfma_f32_16x16x32_bf16(af[mt], wf[nt],
                                                                acc[mt][nt], 0, 0, 0);
    }
  }

#pragma unroll
  for (int nt = 0; nt < 4; ++nt) {
    const int n = n0 + wn + nt * 16 + l16;
    const float bv = ld1(bias, n, f32in);
#pragma unroll
    for (int mt = 0; mt < MT; ++mt) {
#pragma unroll
      for (int r4 = 0; r4 < 4; ++r4) {
        const int m = m0 + wm + mt * 16 + quad * 4 + r4;
        float v = acc[mt][nt][r4] + bv;
        if (RELU) v = fmaxf(v, 0.f);
        C[(size_t)m * NMAT + n] = (bf16)v;
      }
    }
  }
}

// ---------------------------------------------------------------------------
// Sliding-window attention (R8-frozen: 52.9 us, FETCH 12 MB, VGPR 60).
// XCD swizzle: xcd = bid&7 selects the (b,h) pair -> 2 heads' K/V per XCD L2.
// ---------------------------------------------------------------------------
__global__ __launch_bounds__(256) void attn_fwd(const bf16* __restrict__ qkv,
                                                bf16* __restrict__ ctx,
                                                const int* __restrict__ wptr) {
  __shared__ __align__(16) bf16 Vt[2][64][72];   // [buf][dh][key] (+8 pad)
  __shared__ __align__(16) bf16 Pbuf[4][16][72]; // per-wave [q][key] (+8 pad)

  const int t = threadIdx.x;
  const int lane = t & 63;
  const int wave = t >> 6;
  const int l16 = lane & 15;
  const int quad = lane >> 4;

  const int bid = blockIdx.x;
  const int xcd = bid & 7;
  const int jj = bid >> 3;                 // 0..127
  const int pair = xcd * 2 + (jj >> 6);    // 0..15 = (b,h)
  const int qblk = jj & 63;
  const int h = pair & 7;
  const int b = pair >> 3;
  const int qbase = qblk * 64;
  int window = *wptr;
  if (window < 0) window = 0;
  if (window > S_LEN) window = S_LEN;
  const float scale = 0.125f;  // 1/sqrt(64)

  const int qrow = qbase + wave * 16 + l16;
  const bf16* qp = qkv + (size_t)(b * S_LEN + qrow) * QKV_LD + h * DHEAD;
  const bf16x8 qf0 = *(const bf16x8*)(qp + quad * 8);
  const bf16x8 qf1 = *(const bf16x8*)(qp + 32 + quad * 8);

  f32x4 o[4];
#pragma unroll
  for (int nt = 0; nt < 4; ++nt) o[nt] = (f32x4){0.f, 0.f, 0.f, 0.f};
  float lp[4] = {0.f, 0.f, 0.f, 0.f};

  int kstart = qbase - window;
  if (kstart < 0) kstart = 0;
  kstart &= ~63;
  int kend = qbase + 64 + window;
  if (kend > S_LEN) kend = S_LEN;
  const int niter = (kend - kstart + 63) >> 6;

  const int vk = (t & 31) * 2;
  const int vd = (t >> 5) * 8;
  const bf16* vbase = qkv + (size_t)(b * S_LEN) * QKV_LD + 2 * DMODEL + h * DHEAD + vd;
  const bf16* kbase = qkv + (size_t)(b * S_LEN) * QKV_LD + DMODEL + h * DHEAD;

  {  // prologue: stage V tile 0 into Vt[0]
    const bf16* p = vbase + (size_t)(kstart + vk) * QKV_LD;
    const bf16x8 va = *(const bf16x8*)p;
    const bf16x8 vb = *(const bf16x8*)(p + QKV_LD);
#pragma unroll
    for (int j = 0; j < 8; ++j) {
      bf16x2 pr; pr[0] = va[j]; pr[1] = vb[j];
      *(bf16x2*)&Vt[0][vd + j][vk] = pr;
    }
  }

  for (int it = 0; it < niter; ++it) {
    const int kt = kstart + it * 64;
    const int cur = it & 1;
    __syncthreads();

    bf16x8 na, nb;
    const bool have_next = (it + 1 < niter);
    if (have_next) {
      const bf16* p = vbase + (size_t)(kt + 64 + vk) * QKV_LD;
      na = *(const bf16x8*)p;
      nb = *(const bf16x8*)(p + QKV_LD);
    }

    f32x4 s[4];
#pragma unroll
    for (int t4 = 0; t4 < 4; ++t4) s[t4] = (f32x4){0.f, 0.f, 0.f, 0.f};
#pragma unroll
    for (int t4 = 0; t4 < 4; ++t4) {
      const bf16* kp = kbase + (size_t)(kt + t4 * 16 + l16) * QKV_LD;
      const bf16x8 k0 = *(const bf16x8*)(kp + quad * 8);
      const bf16x8 k1 = *(const bf16x8*)(kp + 32 + quad * 8);
      s[t4] = __builtin_amdgcn_mfma_f32_16x16x32_bf16(qf0, k0, s[t4], 0, 0, 0);
      s[t4] = __builtin_amdgcn_mfma_f32_16x16x32_bf16(qf1, k1, s[t4], 0, 0, 0);
    }

#pragma unroll
    for (int r = 0; r < 4; ++r) {
      const int q = qbase + wave * 16 + quad * 4 + r;
      const int lo = q - window, hi = q + window;
      float psum = 0.f;
#pragma unroll
      for (int t4 = 0; t4 < 4; ++t4) {
        const int key = kt + t4 * 16 + l16;
        const float p = (key >= lo && key <= hi) ? __expf(s[t4][r] * scale) : 0.f;
        psum += p;
        Pbuf[wave][quad * 4 + r][t4 * 16 + l16] = (bf16)p;
      }
      lp[r] += psum;
    }

    const bf16x8 pf0 = *(const bf16x8*)&Pbuf[wave][l16][quad * 8];
    const bf16x8 pf1 = *(const bf16x8*)&Pbuf[wave][l16][32 + quad * 8];
#pragma unroll
    for (int nt = 0; nt < 4; ++nt) {
      const bf16x8 v0 = *(const bf16x8*)&Vt[cur][nt * 16 + l16][quad * 8];
      const bf16x8 v1 = *(const bf16x8*)&Vt[cur][nt * 16 + l16][32 + quad * 8];
      o[nt] = __builtin_amdgcn_mfma_f32_16x16x32_bf16(pf0, v0, o[nt], 0, 0, 0);
      o[nt] = __builtin_amdgcn_mfma_f32_16x16x32_bf16(pf1, v1, o[nt], 0, 0, 0);
    }

    if (have_next) {
#pragma unroll
      for (int j = 0; j < 8; ++j) {
        bf16x2 pr; pr[0] = na[j]; pr[1] = nb[j];
        *(bf16x2*)&Vt[cur ^ 1][vd + j][vk] = pr;
      }
    }
  }

#pragma unroll
  for (int r = 0; r < 4; ++r) {
#pragma unroll
    for (int off = 1; off < 16; off <<= 1) lp[r] += __shfl_xor(lp[r], off);
    const float inv = (lp[r] > 0.f) ? (1.0f / lp[r]) : 0.f;
    const int q = qbase + wave * 16 + quad * 4 + r;
#pragma unroll
    for (int nt = 0; nt < 4; ++nt) {
      ctx[(size_t)(b * S_LEN + q) * DMODEL + h * DHEAD + nt * 16 + l16] =
          (bf16)(o[nt][r] * inv);
    }
  }
}

// ---------------------------------------------------------------------------
// Fused residual + LayerNorm (R3-verified). One wave per row, 4 rows/block.
// ---------------------------------------------------------------------------
template <bool A_RAW, bool OUT_RAW>
__global__ __launch_bounds__(256) void ln_fused(const void* __restrict__ a,
                                                const bf16* __restrict__ bres,
                                                const void* __restrict__ g,
                                                const void* __restrict__ be,
                                                void* __restrict__ out,
                                                const int* __restrict__ flag) {
  const bool f32in = (*flag == 0);
  const int row = blockIdx.x * 4 + (threadIdx.x >> 6);
  const int lane = threadIdx.x & 63;
  const size_t base = (size_t)row * DMODEL + lane * 8;
  const bf16x8 va = ld8(a, base, A_RAW && f32in);
  const bf16x8 vb = *(const bf16x8*)(bres + base);
  float v[8], s = 0.f, s2 = 0.f;
#pragma unroll
  for (int j = 0; j < 8; ++j) {
    v[j] = (float)va[j] + (float)vb[j];
    s += v[j];
    s2 += v[j] * v[j];
  }
#pragma unroll
  for (int off = 1; off < 64; off <<= 1) {
    s += __shfl_xor(s, off);
    s2 += __shfl_xor(s2, off);
  }
  const float mean = s * (1.0f / DMODEL);
  float var = s2 * (1.0f / DMODEL) - mean * mean;
  if (var < 0.f) var = 0.f;
  const float rstd = rsqrtf(var + 1e-5f);
  const bf16x8 gv = ld8(g, lane * 8, f32in);
  const bf16x8 bev = ld8(be, lane * 8, f32in);
  float ov[8];
#pragma unroll
  for (int j = 0; j < 8; ++j)
    ov[j] = (v[j] - mean) * rstd * (float)gv[j] + (float)bev[j];
  if (OUT_RAW && f32in) {
    float4 o0 = {ov[0], ov[1], ov[2], ov[3]};
    float4 o1 = {ov[4], ov[5], ov[6], ov[7]};
    *(float4*)((float*)out + base) = o0;
    *(float4*)((float*)out + base + 4) = o1;
  } else {
    bf16x8 ob;
#pragma unroll
    for (int j = 0; j < 8; ++j) ob[j] = (bf16)ov[j];
    *(bf16x8*)((bf16*)out + base) = ob;
  }
}

// ---------------------------------------------------------------------------
extern "C" void kernel_launch(void* const* d_in, const int* in_sizes, int n_in,
                              void* d_out, int out_size, void* d_ws, size_t ws_size,
                              hipStream_t stream) {
  const void* x          = d_in[0];
  const void* in_proj_w  = d_in[1];
  const void* in_proj_b  = d_in[2];
  const void* out_proj_w = d_in[3];
  const void* out_proj_b = d_in[4];
  const void* ln1_g      = d_in[5];
  const void* ln1_b      = d_in[6];
  const void* ln2_g      = d_in[7];
  const void* ln2_b      = d_in[8];
  const void* w1         = d_in[9];
  const void* b1         = d_in[10];
  const void* w2         = d_in[11];
  const void* b2         = d_in[12];
  const int*  wptr       = (const int*)d_in[13];

  // Workspace (28.3 MB): flag | bf16 weight arena (3 MB) | big region:
  // qkv [steps 1-2] then h / a1 / attn_out(mlp). d_out doubles as xb then ctx.
  char* ws = (char*)d_ws;
  int* flag = (int*)ws;
  bf16* warena = (bf16*)(ws + 256);
  bf16* wq = warena;
  bf16* wo = warena + 786432;
  bf16* w1b = warena + 1048576;
  bf16* w2b = warena + 1310720;
  char* big = ws + 256 + 3145728;
  bf16* qkv      = (bf16*)big;
  bf16* h        = (bf16*)big;
  bf16* a1       = (bf16*)(big + 8388608);
  bf16* attn_out = (bf16*)(big + 16777216);
  bf16* mlp      = attn_out;
  bf16* xb       = (bf16*)d_out;
  bf16* ctx      = (bf16*)d_out;

  detect_dtype<<<1, 64, 0, stream>>>((const unsigned int*)x, flag);
  cvt_all<<<2816, 256, 0, stream>>>(x, in_proj_w, out_proj_w, w1, w2, xb, warena, flag);
  // 1. qkv = xb @ in_proj_w^T + b   [M=8192, N=1536], grid 12*64 = 768
  gemm_bt<QKV_LD, 128, false><<<768, 256, 0, stream>>>(
      xb, wq, in_proj_b, qkv, flag);
  // 2. sliding-window attention -> ctx (xb dead from here)
  attn_fwd<<<dim3(BATCH * NHEAD * (S_LEN / 64)), 256, 0, stream>>>(qkv, ctx, wptr);
  // 3. attn_out = ctx @ out_proj_w^T + b   grid 8*64 = 512
  gemm_bt<DMODEL, 64, false><<<512, 256, 0, stream>>>(
      ctx, wo, out_proj_b, attn_out, flag);
  // 4. h = LN(x + attn_out)   (reads raw x: dual-dtype)
  ln_fused<true, false><<<dim3(M_ROWS / 4), 256, 0, stream>>>(
      x, attn_out, ln1_g, ln1_b, h, flag);
  // 5. a1 = relu(h @ w1^T + b1)
  gemm_bt<DMODEL, 64, true><<<512, 256, 0, stream>>>(
      h, w1b, b1, a1, flag);
  // 6. mlp = a1 @ w2^T + b2
  gemm_bt<DMODEL, 64, false><<<512, 256, 0, stream>>>(
      a1, w2b, b2, mlp, flag);
  // 7. out = LN(h + mlp)
  ln_fused<false, true><<<dim3(M_ROWS / 4), 256, 0, stream>>>(
      h, mlp, ln2_g, ln2_b, d_out, flag);
}